// Round 1
// baseline (21521.138 us; speedup 1.0000x reference)
//
#include <hip/hip_runtime.h>
#include <math.h>

#define Hdim 384
#define Tdim 192
#define FH   1536
#define NSEQ 385
#define BSEQ 4
#define NBLK 97   // ceil(385/4)

// ws offsets (floats)
#define OFF_WIH0T 0u          // [384][1536]  Wih0T[k][r] = W_ih[0][r][k]
#define OFF_WHH0T 589824u     // [384][1536]
#define OFF_WIH1T 1179648u    // [384][1536]
#define OFF_WHH1T 1769472u    // [384][1536]
#define OFF_B0    2359296u    // [1536] b_ih[0]+b_hh[0]
#define OFF_B1    2360832u    // [1536]
#define OFF_U     2362368u    // [192][1536] full-seq layer0 ih (incl b0)
#define OFF_Y     2657280u    // [385][192]
// total 2731200 floats = 10.9 MB

__device__ __forceinline__ float sigmoidf_(float v) { return 1.0f / (1.0f + expf(-v)); }

__global__ void prep_transpose(const float* __restrict__ W_ih,
                               const float* __restrict__ W_hh,
                               float* __restrict__ ws) {
  __shared__ float tile[32][33];
  const float* src; float* dst;
  const int z = blockIdx.z;
  if (z == 0)      { src = W_ih;          dst = ws + OFF_WIH0T; }
  else if (z == 1) { src = W_hh;          dst = ws + OFF_WHH0T; }
  else if (z == 2) { src = W_ih + 589824; dst = ws + OFF_WIH1T; }
  else             { src = W_hh + 589824; dst = ws + OFF_WHH1T; }
  const int rb = blockIdx.x * 32;   // src row base (0..1535)
  const int kb = blockIdx.y * 32;   // src col base (0..383)
  const int tx = threadIdx.x, ty = threadIdx.y;
  #pragma unroll
  for (int i = ty; i < 32; i += 8) tile[i][tx] = src[(size_t)(rb + i) * 384 + kb + tx];
  __syncthreads();
  #pragma unroll
  for (int i = ty; i < 32; i += 8) dst[(size_t)(kb + i) * 1536 + rb + tx] = tile[tx][i];
}

__global__ void prep_bias(const float* __restrict__ b_ih, const float* __restrict__ b_hh,
                          float* __restrict__ ws) {
  const int i = blockIdx.x * 256 + threadIdx.x;   // 3072 total
  if (i < 1536) ws[OFF_B0 + i] = b_ih[i] + b_hh[i];
  else if (i < 3072) ws[OFF_B1 + (i - 1536)] = b_ih[i] + b_hh[i];
}

__global__ void prep_ufull(const float* __restrict__ x, float* __restrict__ ws) {
  const float* __restrict__ Wih0T = ws + OFF_WIH0T;
  const float* __restrict__ b0    = ws + OFF_B0;
  float* __restrict__ U           = ws + OFF_U;
  const int t  = blockIdx.x;      // 192
  const int r0 = threadIdx.x;     // 256
  float acc[6];
  #pragma unroll
  for (int u = 0; u < 6; ++u) acc[u] = b0[r0 + 256 * u];
  for (int jv = 0; jv < 384; ++jv) {
    const float xv = x[(size_t)jv * Tdim + t];
    const float* wr = Wih0T + (size_t)jv * FH + r0;
    #pragma unroll
    for (int u = 0; u < 6; ++u) acc[u] = fmaf(wr[256 * u], xv, acc[u]);
  }
  float* Ut = U + (size_t)t * FH + r0;
  #pragma unroll
  for (int u = 0; u < 6; ++u) Ut[256 * u] = acc[u];
}

__global__ __launch_bounds__(384) void lstm_main(const float* __restrict__ x,
                                                 const float* __restrict__ fc_w,
                                                 const float* __restrict__ fc_b,
                                                 float* __restrict__ ws) {
  const float* __restrict__ Wih0T = ws + OFF_WIH0T;
  const float* __restrict__ Whh0T = ws + OFF_WHH0T;
  const float* __restrict__ Wih1T = ws + OFF_WIH1T;
  const float* __restrict__ Whh1T = ws + OFF_WHH1T;
  const float* __restrict__ b0    = ws + OFF_B0;
  const float* __restrict__ b1    = ws + OFF_B1;
  const float* __restrict__ U     = ws + OFF_U;
  float* __restrict__ yout        = ws + OFF_Y;

  __shared__ __align__(16) float h0s[BSEQ][Hdim];
  __shared__ __align__(16) float h1s[BSEQ][Hdim];
  __shared__ float red[BSEQ][8];

  const int k = threadIdx.x;          // hidden index owned by this thread
  const int sbase = blockIdx.x * BSEQ;

  float c0[BSEQ], c1[BSEQ];
  #pragma unroll
  for (int s = 0; s < BSEQ; ++s) { c0[s] = 0.f; c1[s] = 0.f; h0s[s][k] = 0.f; h1s[s][k] = 0.f; }

  const float fcw = fc_w[k];
  const float fcb = fc_b[0];
  const float b0i = b0[k], b0f = b0[384 + k], b0g = b0[768 + k], b0o = b0[1152 + k];
  const float b1i = b1[k], b1f = b1[384 + k], b1g = b1[768 + k], b1o = b1[1152 + k];
  __syncthreads();

  for (int t = 0; t < Tdim; ++t) {
    float ai[BSEQ], af[BSEQ], ag[BSEQ], ao[BSEQ];
    // ---- layer 0 input term (rank-1 trick for masked seqs, U for full seq)
    #pragma unroll
    for (int s = 0; s < BSEQ; ++s) {
      const int seq = sbase + s;
      if (seq == 384) {
        const float* u = U + (size_t)t * FH;
        ai[s] = u[k]; af[s] = u[384 + k]; ag[s] = u[768 + k]; ao[s] = u[1152 + k];
      } else {
        const int sq = (seq < 384) ? seq : 0;
        const float xv = x[(size_t)sq * Tdim + t];
        const float* wr = Wih0T + (size_t)sq * FH;
        ai[s] = fmaf(xv, wr[k],        b0i);
        af[s] = fmaf(xv, wr[384 + k],  b0f);
        ag[s] = fmaf(xv, wr[768 + k],  b0g);
        ao[s] = fmaf(xv, wr[1152 + k], b0o);
      }
    }
    // ---- layer 0 recurrent GEMV
    for (int kk4 = 0; kk4 < Hdim / 4; ++kk4) {
      float4 hv[BSEQ];
      #pragma unroll
      for (int s = 0; s < BSEQ; ++s) hv[s] = *(const float4*)&h0s[s][kk4 * 4];
      #pragma unroll
      for (int u = 0; u < 4; ++u) {
        const float* wr = Whh0T + (size_t)(kk4 * 4 + u) * FH + k;
        const float wi = wr[0], wf = wr[384], wg = wr[768], wo = wr[1152];
        #pragma unroll
        for (int s = 0; s < BSEQ; ++s) {
          const float h = (u == 0) ? hv[s].x : (u == 1) ? hv[s].y : (u == 2) ? hv[s].z : hv[s].w;
          ai[s] = fmaf(h, wi, ai[s]); af[s] = fmaf(h, wf, af[s]);
          ag[s] = fmaf(h, wg, ag[s]); ao[s] = fmaf(h, wo, ao[s]);
        }
      }
    }
    float hn0[BSEQ];
    #pragma unroll
    for (int s = 0; s < BSEQ; ++s) {
      const float ig = sigmoidf_(ai[s]);
      const float fg = sigmoidf_(af[s]);
      const float gg = tanhf(ag[s]);
      const float og = sigmoidf_(ao[s]);
      c0[s] = fg * c0[s] + ig * gg;
      hn0[s] = og * tanhf(c0[s]);
    }
    __syncthreads();                       // A: done reading h0s(old)
    #pragma unroll
    for (int s = 0; s < BSEQ; ++s) h0s[s][k] = hn0[s];
    __syncthreads();                       // B: h0s(new) visible

    // ---- layer 1: z1 = h0(t) @ Wih1^T + h1(t-1) @ Whh1^T + b1
    #pragma unroll
    for (int s = 0; s < BSEQ; ++s) { ai[s] = b1i; af[s] = b1f; ag[s] = b1g; ao[s] = b1o; }
    for (int kk4 = 0; kk4 < Hdim / 4; ++kk4) {
      float4 h0v[BSEQ], h1v[BSEQ];
      #pragma unroll
      for (int s = 0; s < BSEQ; ++s) {
        h0v[s] = *(const float4*)&h0s[s][kk4 * 4];
        h1v[s] = *(const float4*)&h1s[s][kk4 * 4];
      }
      #pragma unroll
      for (int u = 0; u < 4; ++u) {
        const float* wa = Wih1T + (size_t)(kk4 * 4 + u) * FH + k;
        const float* wb = Whh1T + (size_t)(kk4 * 4 + u) * FH + k;
        const float xi_ = wa[0], xf_ = wa[384], xg_ = wa[768], xo_ = wa[1152];
        const float hi_ = wb[0], hf_ = wb[384], hg_ = wb[768], ho_ = wb[1152];
        #pragma unroll
        for (int s = 0; s < BSEQ; ++s) {
          const float ha = (u == 0) ? h0v[s].x : (u == 1) ? h0v[s].y : (u == 2) ? h0v[s].z : h0v[s].w;
          const float hb = (u == 0) ? h1v[s].x : (u == 1) ? h1v[s].y : (u == 2) ? h1v[s].z : h1v[s].w;
          ai[s] = fmaf(ha, xi_, fmaf(hb, hi_, ai[s]));
          af[s] = fmaf(ha, xf_, fmaf(hb, hf_, af[s]));
          ag[s] = fmaf(ha, xg_, fmaf(hb, hg_, ag[s]));
          ao[s] = fmaf(ha, xo_, fmaf(hb, ho_, ao[s]));
        }
      }
    }
    float hn1[BSEQ];
    #pragma unroll
    for (int s = 0; s < BSEQ; ++s) {
      const float ig = sigmoidf_(ai[s]);
      const float fg = sigmoidf_(af[s]);
      const float gg = tanhf(ag[s]);
      const float og = sigmoidf_(ao[s]);
      c1[s] = fg * c1[s] + ig * gg;
      hn1[s] = og * tanhf(c1[s]);
    }
    __syncthreads();                       // C: done reading h1s(old)
    #pragma unroll
    for (int s = 0; s < BSEQ; ++s) h1s[s][k] = hn1[s];
    // ---- y[s][t] = h1 . fc_w + fc_b
    #pragma unroll
    for (int s = 0; s < BSEQ; ++s) {
      float v = hn1[s] * fcw;
      v += __shfl_down(v, 32); v += __shfl_down(v, 16); v += __shfl_down(v, 8);
      v += __shfl_down(v, 4);  v += __shfl_down(v, 2);  v += __shfl_down(v, 1);
      if ((k & 63) == 0) red[s][k >> 6] = v;
    }
    __syncthreads();                       // D
    if (k < BSEQ) {
      const int seq = sbase + k;
      if (seq < NSEQ) {
        float sum = fcb;
        #pragma unroll
        for (int w = 0; w < 6; ++w) sum += red[k][w];
        yout[(size_t)seq * Tdim + t] = sum;
      }
    }
    // next iter's h0s/h1s reads are protected by barriers C,D (+A,B of next iter)
  }
}

__global__ void copy_yi(const float* __restrict__ ws, float* __restrict__ out) {
  const int i = blockIdx.x * 256 + threadIdx.x;
  if (i < 384 * 192) out[192 + i] = ws[OFF_Y + i];
}

__global__ __launch_bounds__(384) void attn_final(const float* __restrict__ ws,
                                                  float* __restrict__ out) {
  __shared__ float sc[384];
  __shared__ float redm[8], reds[8];
  const int j = threadIdx.x;
  const float* y  = ws + OFF_Y;
  const float* ya = y + (size_t)384 * Tdim;   // full-sequence y row
  float dot = 0.f;
  for (int t = 0; t < Tdim; ++t) dot = fmaf(ya[t], y[(size_t)j * Tdim + t], dot);
  float m = dot;
  m = fmaxf(m, __shfl_xor(m, 32)); m = fmaxf(m, __shfl_xor(m, 16));
  m = fmaxf(m, __shfl_xor(m, 8));  m = fmaxf(m, __shfl_xor(m, 4));
  m = fmaxf(m, __shfl_xor(m, 2));  m = fmaxf(m, __shfl_xor(m, 1));
  if ((j & 63) == 0) redm[j >> 6] = m;
  __syncthreads();
  float M = redm[0];
  #pragma unroll
  for (int w = 1; w < 6; ++w) M = fmaxf(M, redm[w]);
  const float e = expf(dot - M);
  float ss = e;
  ss += __shfl_xor(ss, 32); ss += __shfl_xor(ss, 16); ss += __shfl_xor(ss, 8);
  ss += __shfl_xor(ss, 4);  ss += __shfl_xor(ss, 2);  ss += __shfl_xor(ss, 1);
  if ((j & 63) == 0) reds[j >> 6] = ss;
  __syncthreads();
  float S = 0.f;
  #pragma unroll
  for (int w = 0; w < 6; ++w) S += reds[w];
  const float a = e / S;
  sc[j] = a;
  out[192 + 73728 + j] = a;
  __syncthreads();
  if (j < 192) {
    float acc = 0.f;
    for (int jj = 0; jj < 384; ++jj) acc = fmaf(sc[jj], y[(size_t)jj * Tdim + j], acc);
    out[j] = acc;
  }
}

extern "C" void kernel_launch(void* const* d_in, const int* in_sizes, int n_in,
                              void* d_out, int out_size, void* d_ws, size_t ws_size,
                              hipStream_t stream) {
  const float* x    = (const float*)d_in[0];
  const float* W_ih = (const float*)d_in[1];
  const float* W_hh = (const float*)d_in[2];
  const float* b_ih = (const float*)d_in[3];
  const float* b_hh = (const float*)d_in[4];
  const float* fc_w = (const float*)d_in[5];
  const float* fc_b = (const float*)d_in[6];
  float* out = (float*)d_out;
  float* ws  = (float*)d_ws;

  hipLaunchKernelGGL(prep_transpose, dim3(48, 12, 4), dim3(32, 8), 0, stream, W_ih, W_hh, ws);
  hipLaunchKernelGGL(prep_bias,      dim3(12),        dim3(256),   0, stream, b_ih, b_hh, ws);
  hipLaunchKernelGGL(prep_ufull,     dim3(192),       dim3(256),   0, stream, x, ws);
  hipLaunchKernelGGL(lstm_main,      dim3(NBLK),      dim3(384),   0, stream, x, fc_w, fc_b, ws);
  hipLaunchKernelGGL(copy_yi,        dim3(288),       dim3(256),   0, stream, ws, out);
  hipLaunchKernelGGL(attn_final,     dim3(1),         dim3(384),   0, stream, ws, out);
}

// Round 2
// 11158.485 us; speedup vs baseline: 1.9287x; 1.9287x over previous
//
#include <hip/hip_runtime.h>
#include <hip/hip_cooperative_groups.h>
#include <math.h>

namespace cg = cooperative_groups;

typedef __attribute__((ext_vector_type(8))) short sv8;
typedef __attribute__((ext_vector_type(4))) float fv4;
typedef unsigned short u16;

#define SEQP 448
#define NP   1536
#define TDIM 192
#define HD   384

// ---- ws byte offsets ----
#define OFF_B0HI  0u
#define OFF_B0LO  1179648u
#define OFF_B1HI  2359296u
#define OFF_B1LO  4718592u
#define OFF_WIH0P 7077888u   // [448][1536] f32, gate-packed Wih0 columns per seq
#define OFF_U     9830400u   // [192][1536] f32, full-seq layer0 input (no bias)
#define OFF_B0P   11010048u  // [1536] f32
#define OFF_B1P   11016192u
#define OFF_H0HI0 11022336u  // each h buf: 448*384 u16 = 344064 B
#define OFF_H0HI1 11366400u
#define OFF_H0LO0 11710464u
#define OFF_H0LO1 12054528u
#define OFF_H1HI0 12398592u
#define OFF_H1HI1 12742656u
#define OFF_H1LO0 13086720u
#define OFF_H1LO1 13430784u
#define OFF_C0    13774848u  // [448][384] f32
#define OFF_C1    14462976u
#define OFF_YPART 15151104u  // [192][448][24] f32
#define OFF_YY    23408640u  // [448][192] f32

__device__ __forceinline__ u16 f2bf(float v) {
  unsigned u = __builtin_bit_cast(unsigned, v);
  return (u16)((u + 0x7fffu + ((u >> 16) & 1u)) >> 16);
}
__device__ __forceinline__ float bf2f(u16 s) {
  unsigned u = ((unsigned)s) << 16;
  return __builtin_bit_cast(float, u);
}
__device__ __forceinline__ float sigm(float v) { return 1.0f / (1.0f + expf(-v)); }

// ---------------- prep kernels ----------------

// Pack B0 (Whh0) and B1 (Wih1 stacked over Whh1) into split-bf16 fragment layout:
// element (k-row j, col n) stored at ((j>>3)*1536 + n)*8 + (j&7);
// n = (hk/16)*64 + gate*16 + (hk%16), source row n' = gate*384 + hk.
__global__ void pack_weights(const float* __restrict__ W_ih, const float* __restrict__ W_hh,
                             char* __restrict__ wsb) {
  const int idx = blockIdx.x * 256 + threadIdx.x;
  const int NE0 = 384 * 1536;
  const int NE1 = 768 * 1536;
  if (idx < NE0) {
    const int j = idx / 1536, n = idx % 1536;
    const int q = n >> 6, rem = n & 63, g = rem >> 4, kl = rem & 15;
    const int hk = q * 16 + kl;
    const float v = W_hh[(size_t)(g * 384 + hk) * 384 + j];
    const u16 hi = f2bf(v);
    const u16 lo = f2bf(v - bf2f(hi));
    const size_t off = ((size_t)(j >> 3) * 1536 + n) * 8 + (j & 7);
    ((u16*)(wsb + OFF_B0HI))[off] = hi;
    ((u16*)(wsb + OFF_B0LO))[off] = lo;
  } else if (idx < NE0 + NE1) {
    const int i2 = idx - NE0;
    const int j = i2 / 1536, n = i2 % 1536;
    const int q = n >> 6, rem = n & 63, g = rem >> 4, kl = rem & 15;
    const int hk = q * 16 + kl;
    const int nr = g * 384 + hk;
    const float v = (j < 384) ? W_ih[589824 + (size_t)nr * 384 + j]
                              : W_hh[589824 + (size_t)nr * 384 + (j - 384)];
    const u16 hi = f2bf(v);
    const u16 lo = f2bf(v - bf2f(hi));
    const size_t off = ((size_t)(j >> 3) * 1536 + n) * 8 + (j & 7);
    ((u16*)(wsb + OFF_B1HI))[off] = hi;
    ((u16*)(wsb + OFF_B1LO))[off] = lo;
  }
}

// Wih0 packed per-seq fp32 rows (rank-1 input term) + packed biases
__global__ void pack_aux(const float* __restrict__ W_ih, const float* __restrict__ b_ih,
                         const float* __restrict__ b_hh, char* __restrict__ wsb) {
  const int idx = blockIdx.x * 256 + threadIdx.x;
  float* Wp = (float*)(wsb + OFF_WIH0P);
  if (idx < SEQP * 1536) {
    const int seq = idx / 1536, n = idx % 1536;
    const int q = n >> 6, rem = n & 63, g = rem >> 4, kl = rem & 15;
    const int hk = q * 16 + kl;
    Wp[idx] = (seq < 384) ? W_ih[(size_t)(g * 384 + hk) * 384 + seq] : 0.0f;
  }
  if (idx < 1536) {
    const int q = idx >> 6, rem = idx & 63, g = rem >> 4, kl = rem & 15;
    const int nr = g * 384 + (q * 16 + kl);
    ((float*)(wsb + OFF_B0P))[idx] = b_ih[nr] + b_hh[nr];
    ((float*)(wsb + OFF_B1P))[idx] = b_ih[1536 + nr] + b_hh[1536 + nr];
  }
}

// U[t][n] = sum_j x[j,t] * Wih0p[j][n]  (full-sequence layer0 input, no bias)
__global__ __launch_bounds__(256) void compute_U(const float* __restrict__ x,
                                                 char* __restrict__ wsb) {
  const float* Wp = (const float*)(wsb + OFF_WIH0P);
  float* U = (float*)(wsb + OFF_U);
  __shared__ float xs[384];
  const int t = blockIdx.x;
  for (int j = threadIdx.x; j < 384; j += 256) xs[j] = x[(size_t)j * TDIM + t];
  __syncthreads();
  for (int n = threadIdx.x; n < 1536; n += 256) {
    float a = 0.0f;
    for (int j = 0; j < 384; ++j) a = fmaf(xs[j], Wp[(size_t)j * NP + n], a);
    U[(size_t)t * NP + n] = a;
  }
}

// ---------------- main cooperative kernel ----------------

__device__ __forceinline__ void gemm_k12(fv4 acc[4], const u16* aH, const u16* aL,
                                         const u16* Bhi, const u16* Blo,
                                         int browBase, int n0, int lrow, int lkc) {
  const size_t bb = ((size_t)(browBase + lkc) * NP + n0 + lrow) * 8;
  #pragma unroll 4
  for (int kc = 0; kc < 12; ++kc) {
    const sv8 ah = *(const sv8*)(aH + kc * 32);
    const sv8 al = *(const sv8*)(aL + kc * 32);
    const size_t bo = bb + (size_t)kc * 4 * NP * 8;
    #pragma unroll
    for (int g = 0; g < 4; ++g) {
      const sv8 bh = *(const sv8*)(Bhi + bo + g * 16 * 8);
      const sv8 bl = *(const sv8*)(Blo + bo + g * 16 * 8);
      acc[g] = __builtin_amdgcn_mfma_f32_16x16x32_bf16(ah, bh, acc[g], 0, 0, 0);
      acc[g] = __builtin_amdgcn_mfma_f32_16x16x32_bf16(ah, bl, acc[g], 0, 0, 0);
      acc[g] = __builtin_amdgcn_mfma_f32_16x16x32_bf16(al, bh, acc[g], 0, 0, 0);
    }
  }
}

__device__ __forceinline__ void l0_job(int mt, int kg, int t,
    const u16* h0hiP, const u16* h0loP, u16* h0hiC, u16* h0loC,
    const u16* B0hi, const u16* B0lo,
    const float* Wp, const float* U, const float* b0p, const float* x,
    float* c0, int lrow, int lkc, int wv) {
  const int seq0 = mt * 64 + wv * 16;
  const int rowA = seq0 + lrow;
  const int n0 = kg * 64;
  fv4 acc[4] = {{0.f,0.f,0.f,0.f},{0.f,0.f,0.f,0.f},{0.f,0.f,0.f,0.f},{0.f,0.f,0.f,0.f}};
  const u16* aH = h0hiP + (size_t)rowA * HD + lkc * 8;
  const u16* aL = h0loP + (size_t)rowA * HD + lkc * 8;
  gemm_k12(acc, aH, aL, B0hi, B0lo, 0, n0, lrow, lkc);
  const int ke = kg * 16 + lrow;
  const float bi = b0p[n0 + lrow], bf_ = b0p[n0 + 16 + lrow],
              bg = b0p[n0 + 32 + lrow], bo_ = b0p[n0 + 48 + lrow];
  #pragma unroll
  for (int r = 0; r < 4; ++r) {
    const int seq = seq0 + lkc * 4 + r;
    float zi = acc[0][r] + bi, zf = acc[1][r] + bf_,
          zg = acc[2][r] + bg, zo = acc[3][r] + bo_;
    if (seq < 384) {
      const float xv = x[(size_t)seq * TDIM + t];
      const float* wr = Wp + (size_t)seq * NP + n0 + lrow;
      zi = fmaf(xv, wr[0], zi);  zf = fmaf(xv, wr[16], zf);
      zg = fmaf(xv, wr[32], zg); zo = fmaf(xv, wr[48], zo);
    } else if (seq == 384) {
      const float* ur = U + (size_t)t * NP + n0 + lrow;
      zi += ur[0]; zf += ur[16]; zg += ur[32]; zo += ur[48];
    }
    float* cp = c0 + (size_t)seq * HD + ke;
    const float cold = *cp;
    const float ig = sigm(zi), fg = sigm(zf), gv = tanhf(zg), og = sigm(zo);
    const float cn = fg * cold + ig * gv;
    *cp = cn;
    const float h = og * tanhf(cn);
    const u16 hh = f2bf(h);
    const u16 hl = f2bf(h - bf2f(hh));
    const size_t ho = (size_t)seq * HD + ke;
    h0hiC[ho] = hh; h0loC[ho] = hl;
  }
}

__device__ __forceinline__ void l1_job(int mt, int kg, int t,
    const u16* h0hiC, const u16* h0loC,
    const u16* h1hiP, const u16* h1loP, u16* h1hiC, u16* h1loC,
    const u16* B1hi, const u16* B1lo,
    const float* b1p, const float* fc_w,
    float* c1, float* Yp, int lrow, int lkc, int wv) {
  const int seq0 = mt * 64 + wv * 16;
  const int rowA = seq0 + lrow;
  const int n0 = kg * 64;
  fv4 acc[4] = {{0.f,0.f,0.f,0.f},{0.f,0.f,0.f,0.f},{0.f,0.f,0.f,0.f},{0.f,0.f,0.f,0.f}};
  gemm_k12(acc, h0hiC + (size_t)rowA * HD + lkc * 8, h0loC + (size_t)rowA * HD + lkc * 8,
           B1hi, B1lo, 0, n0, lrow, lkc);
  gemm_k12(acc, h1hiP + (size_t)rowA * HD + lkc * 8, h1loP + (size_t)rowA * HD + lkc * 8,
           B1hi, B1lo, 48, n0, lrow, lkc);
  const int ke = kg * 16 + lrow;
  const float fcwk = fc_w[ke];
  const float bi = b1p[n0 + lrow], bf_ = b1p[n0 + 16 + lrow],
              bg = b1p[n0 + 32 + lrow], bo_ = b1p[n0 + 48 + lrow];
  #pragma unroll
  for (int r = 0; r < 4; ++r) {
    const int seq = seq0 + lkc * 4 + r;
    float zi = acc[0][r] + bi, zf = acc[1][r] + bf_,
          zg = acc[2][r] + bg, zo = acc[3][r] + bo_;
    float* cp = c1 + (size_t)seq * HD + ke;
    const float cold = *cp;
    const float ig = sigm(zi), fg = sigm(zf), gv = tanhf(zg), og = sigm(zo);
    const float cn = fg * cold + ig * gv;
    *cp = cn;
    const float h = og * tanhf(cn);
    const u16 hh = f2bf(h);
    const u16 hl = f2bf(h - bf2f(hh));
    const size_t ho = (size_t)seq * HD + ke;
    h1hiC[ho] = hh; h1loC[ho] = hl;
    // y partial: reduce h*fcw over the 16 lanes of this lane-group
    float yv = h * fcwk;
    yv += __shfl_xor(yv, 1); yv += __shfl_xor(yv, 2);
    yv += __shfl_xor(yv, 4); yv += __shfl_xor(yv, 8);
    if (lrow == 0) Yp[((size_t)t * SEQP + seq) * 24 + kg] = yv;
  }
}

__global__ __launch_bounds__(256, 2) void lstm_coop(const float* __restrict__ x,
                                                    const float* __restrict__ fc_w,
                                                    char* __restrict__ wsb) {
  const u16* B0hi = (const u16*)(wsb + OFF_B0HI);
  const u16* B0lo = (const u16*)(wsb + OFF_B0LO);
  const u16* B1hi = (const u16*)(wsb + OFF_B1HI);
  const u16* B1lo = (const u16*)(wsb + OFF_B1LO);
  const float* Wp  = (const float*)(wsb + OFF_WIH0P);
  const float* U   = (const float*)(wsb + OFF_U);
  const float* b0p = (const float*)(wsb + OFF_B0P);
  const float* b1p = (const float*)(wsb + OFF_B1P);
  float* c0 = (float*)(wsb + OFF_C0);
  float* c1 = (float*)(wsb + OFF_C1);
  float* Yp = (float*)(wsb + OFF_YPART);

  const int tid  = threadIdx.x;
  const int lane = tid & 63;
  const int wv   = tid >> 6;
  const int lrow = lane & 15;
  const int lkc  = lane >> 4;

  const int bid = blockIdx.x;
  const bool isL1 = (bid >= 84);
  const int jA = isL1 ? (bid - 84) : (2 * bid);
  const int jB = isL1 ? 0 : (2 * bid + 1);

  cg::grid_group grid = cg::this_grid();

  for (int p = 0; p <= TDIM; ++p) {
    if (!isL1) {
      if (p < TDIM) {
        u16* h0hiC = (u16*)(wsb + ((p & 1) ? OFF_H0HI1 : OFF_H0HI0));
        u16* h0loC = (u16*)(wsb + ((p & 1) ? OFF_H0LO1 : OFF_H0LO0));
        const u16* h0hiP = (const u16*)(wsb + ((p & 1) ? OFF_H0HI0 : OFF_H0HI1));
        const u16* h0loP = (const u16*)(wsb + ((p & 1) ? OFF_H0LO0 : OFF_H0LO1));
        l0_job(jA / 24, jA % 24, p, h0hiP, h0loP, h0hiC, h0loC, B0hi, B0lo,
               Wp, U, b0p, x, c0, lrow, lkc, wv);
        l0_job(jB / 24, jB % 24, p, h0hiP, h0loP, h0hiC, h0loC, B0hi, B0lo,
               Wp, U, b0p, x, c0, lrow, lkc, wv);
      }
    } else {
      if (p >= 1) {
        const int t = p - 1;
        const u16* h0hiC = (const u16*)(wsb + ((t & 1) ? OFF_H0HI1 : OFF_H0HI0));
        const u16* h0loC = (const u16*)(wsb + ((t & 1) ? OFF_H0LO1 : OFF_H0LO0));
        const u16* h1hiP = (const u16*)(wsb + ((t & 1) ? OFF_H1HI0 : OFF_H1HI1));
        const u16* h1loP = (const u16*)(wsb + ((t & 1) ? OFF_H1LO0 : OFF_H1LO1));
        u16* h1hiC = (u16*)(wsb + ((t & 1) ? OFF_H1HI1 : OFF_H1HI0));
        u16* h1loC = (u16*)(wsb + ((t & 1) ? OFF_H1LO1 : OFF_H1LO0));
        l1_job(jA / 24, jA % 24, t, h0hiC, h0loC, h1hiP, h1loP, h1hiC, h1loC,
               B1hi, B1lo, b1p, fc_w, c1, Yp, lrow, lkc, wv);
      }
    }
    grid.sync();
  }
}

// ---------------- epilogue kernels ----------------

__global__ void y_final(const float* __restrict__ fc_b, char* __restrict__ wsb) {
  const float* Yp = (const float*)(wsb + OFF_YPART);
  float* Y = (float*)(wsb + OFF_YY);
  const int t = blockIdx.x;
  const int seq = threadIdx.x;
  if (seq < 385) {
    const float* p = Yp + ((size_t)t * SEQP + seq) * 24;
    float s = fc_b[0];
    #pragma unroll
    for (int k = 0; k < 24; ++k) s += p[k];
    Y[(size_t)seq * TDIM + t] = s;
  }
}

__global__ void copy_yi(char* __restrict__ wsb, float* __restrict__ out) {
  const float* Y = (const float*)(wsb + OFF_YY);
  const int i = blockIdx.x * 256 + threadIdx.x;
  if (i < 384 * 192) out[192 + i] = Y[i];
}

__global__ __launch_bounds__(384) void attn_final(char* __restrict__ wsb,
                                                  float* __restrict__ out) {
  const float* Y = (const float*)(wsb + OFF_YY);
  __shared__ float sc[384];
  __shared__ float redm[8], reds[8];
  const int j = threadIdx.x;
  const float* ya = Y + (size_t)384 * TDIM;
  float dot = 0.f;
  for (int t = 0; t < TDIM; ++t) dot = fmaf(ya[t], Y[(size_t)j * TDIM + t], dot);
  float m = dot;
  m = fmaxf(m, __shfl_xor(m, 32)); m = fmaxf(m, __shfl_xor(m, 16));
  m = fmaxf(m, __shfl_xor(m, 8));  m = fmaxf(m, __shfl_xor(m, 4));
  m = fmaxf(m, __shfl_xor(m, 2));  m = fmaxf(m, __shfl_xor(m, 1));
  if ((j & 63) == 0) redm[j >> 6] = m;
  __syncthreads();
  float M = redm[0];
  #pragma unroll
  for (int w = 1; w < 6; ++w) M = fmaxf(M, redm[w]);
  const float e = expf(dot - M);
  float ss = e;
  ss += __shfl_xor(ss, 32); ss += __shfl_xor(ss, 16); ss += __shfl_xor(ss, 8);
  ss += __shfl_xor(ss, 4);  ss += __shfl_xor(ss, 2);  ss += __shfl_xor(ss, 1);
  if ((j & 63) == 0) reds[j >> 6] = ss;
  __syncthreads();
  float S = 0.f;
  #pragma unroll
  for (int w = 0; w < 6; ++w) S += reds[w];
  const float a = e / S;
  sc[j] = a;
  out[192 + 73728 + j] = a;
  __syncthreads();
  if (j < 192) {
    float acc = 0.f;
    for (int jj = 0; jj < 384; ++jj) acc = fmaf(sc[jj], Y[(size_t)jj * TDIM + j], acc);
    out[j] = acc;
  }
}

extern "C" void kernel_launch(void* const* d_in, const int* in_sizes, int n_in,
                              void* d_out, int out_size, void* d_ws, size_t ws_size,
                              hipStream_t stream) {
  const float* x    = (const float*)d_in[0];
  const float* W_ih = (const float*)d_in[1];
  const float* W_hh = (const float*)d_in[2];
  const float* b_ih = (const float*)d_in[3];
  const float* b_hh = (const float*)d_in[4];
  const float* fc_w = (const float*)d_in[5];
  const float* fc_b = (const float*)d_in[6];
  float* out = (float*)d_out;
  char* wsb  = (char*)d_ws;

  // zero h/c state region (h0/h1 hi+lo double-buffers + c0/c1)
  hipMemsetAsync(wsb + OFF_H0HI0, 0, OFF_YPART - OFF_H0HI0, stream);
  hipLaunchKernelGGL(pack_weights, dim3(6912), dim3(256), 0, stream, W_ih, W_hh, wsb);
  hipLaunchKernelGGL(pack_aux,     dim3(2688), dim3(256), 0, stream, W_ih, b_ih, b_hh, wsb);
  hipLaunchKernelGGL(compute_U,    dim3(192),  dim3(256), 0, stream, x, wsb);

  void* args[] = {(void*)&x, (void*)&fc_w, (void*)&wsb};
  hipLaunchCooperativeKernel((void*)lstm_coop, dim3(252), dim3(256), args, 0, stream);

  hipLaunchKernelGGL(y_final,  dim3(192), dim3(448), 0, stream, fc_b, wsb);
  hipLaunchKernelGGL(copy_yi,  dim3(288), dim3(256), 0, stream, wsb, out);
  hipLaunchKernelGGL(attn_final, dim3(1), dim3(384), 0, stream, wsb, out);
}